// Round 11
// baseline (145.681 us; speedup 1.0000x reference)
//
#include <hip/hip_runtime.h>
#include <math.h>

#define NROWS 262144
#define NBLK  1024
#define NTHR  256
#define LOG2PI_F 1.8378770664093453f
#define L2E_F   1.4426950408889634f
#define LN2_F   0.6931471805599453f

#define EXP2F(x) __builtin_amdgcn_exp2f(x)
#define LOG2F(x) __builtin_amdgcn_logf(x)

typedef float f32x2 __attribute__((ext_vector_type(2)));

// packed fp32 math: full-rate on CDNA (gfx90a+). A += X*M elementwise on 2 lanes.
#define PKFMA(A, X, M) asm("v_pk_fma_f32 %0, %1, %2, %0" : "+v"(A) : "v"(X), "s"(M))
#define PKADD(A, B)    asm("v_pk_add_f32 %0, %1, %0"     : "+v"(A) : "v"(B))

// ws float layout: wacc[1024]@0 | wzs[1024]@1024 | wmn[16384]@2048 | wmx[16384]@18432 | cons[256]@34816
#define WS_ZS   1024
#define WS_MN   2048
#define WS_MX   18432
#define WS_CONS 34816

template<int CTRL>
__device__ __forceinline__ float dppf(float x){
  return __int_as_float(__builtin_amdgcn_update_dpp(0, __float_as_int(x), CTRL, 0xF, 0xF, true));
}
__device__ __forceinline__ float rl63(float x){
  return __int_as_float(__builtin_amdgcn_readlane(__float_as_int(x), 63));
}
__device__ __forceinline__ float wsum(float x){
  x += dppf<0x111>(x); x += dppf<0x112>(x); x += dppf<0x114>(x); x += dppf<0x118>(x);
  x += dppf<0x142>(x); x += dppf<0x143>(x);
  return rl63(x);
}

// per-k constants: {Elpk, ir*L2E, Dk*L2E, Bk*L2E}
__global__ void setup_k(const float* __restrict__ mu, const float* __restrict__ pi,
                        const float* __restrict__ rr, float* __restrict__ ws){
  int k = threadIdx.x;                       // 64 threads
  float pik = pi[k], rk = rr[k];
  float mumu = 0.f;
  #pragma unroll
  for (int d = 0; d < 16; ++d){ float m = mu[k*16+d]; mumu = fmaf(m, m, mumu); }
  float lse_pi = __logf(wsum(__expf(pik)));  // pi in [0,1]: exp safe
  float lpk = pik - lse_pi;
  float ir = __expf(-rk), Bk = -0.5f*ir;
  float Dk = fmaf(Bk, mumu, -8.f*(rk + LOG2PI_F));
  float* cons = ws + WS_CONS;
  cons[k*4+0] = __expf(lpk);
  cons[k*4+1] = ir*L2E_F;
  cons[k*4+2] = Dk*L2E_F;
  cons[k*4+3] = Bk*L2E_F;
}

// lane = row; z via per-wave [64][18] LDS tile in 4 chunks of 16 k (stride-18:
// 8B-aligned b64 reads, conflict-free). Packed-fp32 dot. min/max deferred.
__global__ __launch_bounds__(NTHR, 6)
void zmain(const float* __restrict__ met, const float* __restrict__ mu,
           const float* __restrict__ z, float* __restrict__ ws)
{
  __shared__ float smem[4608];               // 4 wave-tiles [64][18]; reused as scr (needs 2120)
  const int tid = threadIdx.x, lane = tid & 63, wid = tid >> 6;
  const int bx = blockIdx.x;
  float* zt = smem + wid*1152;

  const int rw0 = bx*256 + wid*64;           // wave's first row
  // ---- met row into reg pairs + ||x||^2 (lane's own row: 64B/lane, dense) ----
  const f32x2* xr2 = (const f32x2*)(met + (size_t)(rw0 + lane)*16);
  f32x2 X[8];
  #pragma unroll
  for (int j=0;j<8;++j) X[j] = xr2[j];
  float xx = 0.f;
  #pragma unroll
  for (int j=0;j<8;++j){ xx = fmaf(X[j].x, X[j].x, xx); xx = fmaf(X[j].y, X[j].y, xx); }

  // ---- z chunk staging: lane l loads float4 (l&3) of tile-row (l>>2)+16i ----
  const float4* z4 = (const float4*)z;
  const int rsub = lane >> 2, kq = lane & 3;
  const float4* cons4 = (const float4*)(ws + WS_CONS);  // uniform -> s_load
  const f32x2*  mu2   = (const f32x2*)mu;               // uniform -> s_load pairs

  float sez=0.f, seu=0.f, sea=0.f, m2=-1e30f, szA=0.f;
  float4 pf0, pf1, pf2, pf3;

#define LOADC(C) { \
    pf0 = z4[(size_t)(rw0 +  0 + rsub)*16 + (C)*4 + kq]; \
    pf1 = z4[(size_t)(rw0 + 16 + rsub)*16 + (C)*4 + kq]; \
    pf2 = z4[(size_t)(rw0 + 32 + rsub)*16 + (C)*4 + kq]; \
    pf3 = z4[(size_t)(rw0 + 48 + rsub)*16 + (C)*4 + kq]; }

#define STORC() { \
    int b = rsub*18 + kq*4; \
    zt[b]=pf0.x; zt[b+1]=pf0.y; zt[b+2]=pf0.z; zt[b+3]=pf0.w; b += 288; \
    zt[b]=pf1.x; zt[b+1]=pf1.y; zt[b+2]=pf1.z; zt[b+3]=pf1.w; b += 288; \
    zt[b]=pf2.x; zt[b+1]=pf2.y; zt[b+2]=pf2.z; zt[b+3]=pf2.w; b += 288; \
    zt[b]=pf3.x; zt[b+1]=pf3.y; zt[b+2]=pf3.z; zt[b+3]=pf3.w; }

#define STEP1(ZV, K) { \
    float4 cc = cons4[K]; \
    const f32x2* Mp = mu2 + (size_t)(K)*8; \
    float zk2 = (ZV)*L2E_F; \
    szA += (ZV); \
    sez += EXP2F(zk2); \
    seu = fmaf(cc.x, EXP2F(-0.1f*zk2), seu); \
    f32x2 A0 = {0.f,0.f}, A1 = {0.f,0.f}; \
    PKFMA(A0, X[0], Mp[0]); PKFMA(A1, X[1], Mp[1]); \
    PKFMA(A0, X[2], Mp[2]); PKFMA(A1, X[3], Mp[3]); \
    PKFMA(A0, X[4], Mp[4]); PKFMA(A1, X[5], Mp[5]); \
    PKFMA(A0, X[6], Mp[6]); PKFMA(A1, X[7], Mp[7]); \
    PKADD(A0, A1); \
    float dt = A0.x + A0.y; \
    float t1  = fmaf(cc.w, xx, zk2) + cc.z; \
    float av2 = fmaf(cc.y, dt, t1); \
    float d2 = av2 - m2; \
    float ee = EXP2F(-fabsf(d2)); \
    bool fl = d2 > 0.f; \
    sea = fmaf(sea, fl?ee:1.f, fl?1.f:ee); \
    m2 = fmaxf(m2, av2); }

  LOADC(0)
  #pragma unroll
  for (int c = 0; c < 4; ++c){
    STORC()                                   // same-wave DS ordering vs prior chunk's reads
    if (c == 0) LOADC(1)
    else if (c == 1) LOADC(2)
    else if (c == 2) LOADC(3)
    #pragma unroll
    for (int g = 0; g < 4; ++g){
      f32x2 za = *(const f32x2*)&zt[lane*18 + g*4];      // fuses to ds_read2_b64
      f32x2 zb = *(const f32x2*)&zt[lane*18 + g*4 + 2];
      STEP1(za.x, c*16 + g*4 + 0)
      STEP1(za.y, c*16 + g*4 + 1)
      STEP1(zb.x, c*16 + g*4 + 2)
      STEP1(zb.y, c*16 + g*4 + 3)
    }
  }
#undef STEP1
#undef STORC
#undef LOADC

  // ---- per-row epilogue (base-2 logs, fold ln2 once) ----
  float accA = LN2_F * (fmaf(63.f, LOG2F(sez), m2 + LOG2F(sea)) - 64.f*LOG2F(seu));

  // ---- deferred per-dim min/max pass (met is L2/L3-resident; regs free now) ----
  float pmn[4], pmx[4];
  #pragma unroll
  for (int j=0;j<4;++j){ pmn[j]=INFINITY; pmx[j]=-INFINITY; }
  {
    const float4* mb = (const float4*)(met + (size_t)bx*4096);
    #pragma unroll
    for (int i=0;i<4;++i){
      float4 v = mb[i*256 + tid];            // slot j tracks dim (4*tid+j)&15
      pmn[0]=fminf(pmn[0],v.x); pmx[0]=fmaxf(pmx[0],v.x);
      pmn[1]=fminf(pmn[1],v.y); pmx[1]=fmaxf(pmx[1],v.y);
      pmn[2]=fminf(pmn[2],v.z); pmx[2]=fmaxf(pmx[2],v.z);
      pmn[3]=fminf(pmn[3],v.w); pmx[3]=fmaxf(pmx[3],v.w);
    }
  }

  // ---- block reduction: reuse smem as scratch (tiles dead after barrier) ----
  __syncthreads();
  float* scr = smem;                          // smn 0..1055, smx 1056..2111, waves 2112..2119
  float wa = wsum(accA), wz = wsum(szA);
  if (lane == 0){ scr[2112 + wid] = wa; scr[2116 + wid] = wz; }
  __syncthreads();
  #pragma unroll
  for (int j=0;j<4;++j){
    int d = (4*tid + j) & 15;
    scr[       d*66 + (tid>>2)] = pmn[j];
    scr[1056 + d*66 + (tid>>2)] = pmx[j];
  }
  __syncthreads();
  if (tid == 0){
    ws[bx]         = scr[2112]+scr[2113]+scr[2114]+scr[2115];
    ws[WS_ZS + bx] = scr[2116]+scr[2117]+scr[2118]+scr[2119];
  }
  if (tid < 16){
    float mnv = INFINITY, mxv = -INFINITY;
    for (int c2=0;c2<64;++c2){
      mnv = fminf(mnv, scr[tid*66+c2]);
      mxv = fmaxf(mxv, scr[1056+tid*66+c2]);
    }
    ws[WS_MN + bx*16 + tid] = mnv;
    ws[WS_MX + bx*16 + tid] = mxv;
  }
}

__global__ __launch_bounds__(NTHR)
void fin_k(const float* __restrict__ mu, const float* __restrict__ pi,
           const float* __restrict__ lam, const float* __restrict__ bp,
           const float* __restrict__ Cv,  const float* __restrict__ rr,
           const float* __restrict__ ws,  float* __restrict__ out,
           float cgam, float lamconst, float lg_c, float lg_g)
{
  __shared__ double sda[NTHR], sdz[NTHR];
  __shared__ float smn[16][66], smx[16][66];
  __shared__ float Rfin[16], vars[16];
  const int tid = threadIdx.x;

  {
    const float4* wa4 = (const float4*)ws;
    const float4* wz4 = (const float4*)(ws + WS_ZS);
    float4 a = wa4[tid], zz = wz4[tid];
    sda[tid] = (double)a.x + (double)a.y + (double)a.z + (double)a.w;
    sdz[tid] = (double)zz.x + (double)zz.y + (double)zz.z + (double)zz.w;
  }
  float pmn[4], pmx[4];
  #pragma unroll
  for (int j=0;j<4;++j){ pmn[j]=INFINITY; pmx[j]=-INFINITY; }
  {
    const float4* mn4 = (const float4*)(ws + WS_MN);
    const float4* mx4 = (const float4*)(ws + WS_MX);
    #pragma unroll
    for (int i=0;i<16;++i){
      float4 v = mn4[i*256 + tid];
      pmn[0]=fminf(pmn[0],v.x); pmn[1]=fminf(pmn[1],v.y);
      pmn[2]=fminf(pmn[2],v.z); pmn[3]=fminf(pmn[3],v.w);
      float4 w = mx4[i*256 + tid];
      pmx[0]=fmaxf(pmx[0],w.x); pmx[1]=fmaxf(pmx[1],w.y);
      pmx[2]=fmaxf(pmx[2],w.z); pmx[3]=fmaxf(pmx[3],w.w);
    }
  }
  #pragma unroll
  for (int j=0;j<4;++j){
    int d = (4*tid + j) & 15;
    smn[d][tid>>2] = pmn[j];
    smx[d][tid>>2] = pmx[j];
  }
  __syncthreads();
  for (int s = NTHR/2; s > 0; s >>= 1){
    if (tid < s){ sda[tid] += sda[tid+s]; sdz[tid] += sdz[tid+s]; }
    __syncthreads();
  }
  if (tid < 16){
    float mnv = INFINITY, mxv = -INFINITY;
    for (int c2=0;c2<64;++c2){ mnv = fminf(mnv, smn[tid][c2]); mxv = fmaxf(mxv, smx[tid][c2]); }
    float Rd = mxv - mnv;
    Rfin[tid] = Rd;
    float l = lam[tid];
    vars[tid] = l*l*Rd;
  }
  __syncthreads();

  if (tid < 64){
    int kk = tid;
    float sumR2 = 0.f;
    #pragma unroll
    for (int dd = 0; dd < 16; ++dd) sumR2 = fmaf(Rfin[dd], Rfin[dd], sumR2);
    float G = 0.025f * sqrtf(sumR2);          // c/(50g)*||R||, c=5, g=4

    float pik2 = pi[kk];
    float sp   = wsum(pik2);
    float lse2 = __logf(wsum(__expf(pik2)));
    float slogpi = sp - 64.f*lse2;

    float qsum = 0.f, slv = 0.f, bb = 0.f;
    #pragma unroll
    for (int dd = 0; dd < 16; ++dd){
      float df = mu[kk*16+dd] - bp[kk*16+dd];
      qsum += df*df / vars[dd];
      slv  += __logf(vars[dd]);
      float bv = bp[kk*16+dd];
      bb = fmaf(bv, bv, bb);
    }
    float mu_term = 0.5f*qsum + 0.5f*slv + 8.0f*LOG2PI_F;
    float rk2 = rr[kk], Ck = Cv[kk];
    float r_lp = 5.f*__logf(Ck) - 4.f*rk2 - Ck*__expf(-rk2) - lg_c;  // c=5
    float C_lp = 4.f*__logf(G)  - 3.f*Ck  - G*__expf(-Ck)  - lg_g;   // g=4
    float lam_term = 0.f;
    if (kk < 16){ float l = lam[kk]; lam_term = lamconst - 0.5f*l - 0.5f*__expf(l); }

    float per = mu_term + 0.5f*bb - r_lp - C_lp - lam_term;
    float persum = wsum(per);

    if (kk == 0){
      double zpart = sda[0] + 262144.0*(double)(cgam + slogpi) - 1.1*sdz[0];
      double tot = (double)persum
                 + (1.0 - 1.0/64.0)*(double)slogpi
                 + 512.0*(double)LOG2PI_F
                 - zpart;                     // z_loss = -zpart
      out[0] = (float)tot;
    }
  }
}

extern "C" void kernel_launch(void* const* d_in, const int* in_sizes, int n_in,
                              void* d_out, int out_size, void* d_ws, size_t ws_size,
                              hipStream_t stream) {
  const float* met = (const float*)d_in[0];
  const float* mu  = (const float*)d_in[1];
  const float* pi  = (const float*)d_in[2];
  const float* lam = (const float*)d_in[3];
  const float* bpp = (const float*)d_in[4];
  const float* Cv  = (const float*)d_in[5];
  const float* rr  = (const float*)d_in[6];
  const float* zz  = (const float*)d_in[7];
  float* out = (float*)d_out;
  float* ws  = (float*)d_ws;

  float cgam     = (float)(lgamma(64.0) + 63.0*log(0.1));
  float lamconst = (float)(0.5*log(0.5) - lgamma(0.5));
  float lg_c     = (float)lgamma(5.0);    // c = 1.25 + 15/4 = 5
  float lg_g     = (float)lgamma(4.0);    // g = 0.25 + 15/4 = 4

  setup_k<<<dim3(1), dim3(64), 0, stream>>>(mu, pi, rr, ws);
  zmain<<<dim3(NBLK), dim3(NTHR), 0, stream>>>(met, mu, zz, ws);
  fin_k<<<dim3(1), dim3(NTHR), 0, stream>>>(mu, pi, lam, bpp, Cv, rr, ws, out,
                                            cgam, lamconst, lg_c, lg_g);
}